// Round 1
// baseline (183.617 us; speedup 1.0000x reference)
//
#include <hip/hip_runtime.h>

// log1p thresholds (fp32): ln(6), ln(26), ln(51)
#define THR1 1.7917594909667969f
#define THR2 3.2580966949462891f
#define THR3 3.9318256378173828f
#define W1 0.2f
#define W2 30.0f
#define W3 2500.0f
#define W4 20000.0f

__device__ __forceinline__ float bucket_w(float y) {
    return (y < THR1) ? W1 : ((y < THR2) ? W2 : ((y < THR3) ? W3 : W4));
}

__global__ __launch_bounds__(256) void mae_partial_kernel(
    const float* __restrict__ y_pred,
    const float* __restrict__ y_true,
    float* __restrict__ acc,   // acc[0]=num, acc[1]=den (pre-zeroed)
    int n)
{
    const int n4 = n >> 2;          // number of float4 groups
    const int rem = n & 3;
    const float4* __restrict__ p4 = (const float4*)y_pred;
    const float4* __restrict__ t4 = (const float4*)y_true;

    float num = 0.0f, den = 0.0f;

    int idx = blockIdx.x * blockDim.x + threadIdx.x;
    const int stride = gridDim.x * blockDim.x;

    for (int i = idx; i < n4; i += stride) {
        const float4 a = p4[i];
        const float4 b = t4[i];

        float w;
        w = bucket_w(b.x); num += w * fabsf(b.x - a.x); den += w;
        w = bucket_w(b.y); num += w * fabsf(b.y - a.y); den += w;
        w = bucket_w(b.z); num += w * fabsf(b.z - a.z); den += w;
        w = bucket_w(b.w); num += w * fabsf(b.w - a.w); den += w;
    }

    // scalar tail (n % 4 elements) handled by the first `rem` global threads
    if (idx < rem) {
        const int j = n4 * 4 + idx;
        const float a = y_pred[j];
        const float b = y_true[j];
        const float w = bucket_w(b);
        num += w * fabsf(b - a);
        den += w;
    }

    // 64-lane wave reduction
    #pragma unroll
    for (int off = 32; off > 0; off >>= 1) {
        num += __shfl_down(num, off, 64);
        den += __shfl_down(den, off, 64);
    }

    // per-block LDS reduction across the 4 waves
    __shared__ float s_num[4];
    __shared__ float s_den[4];
    const int wave = threadIdx.x >> 6;
    const int lane = threadIdx.x & 63;
    if (lane == 0) { s_num[wave] = num; s_den[wave] = den; }
    __syncthreads();

    if (threadIdx.x == 0) {
        const float bn = s_num[0] + s_num[1] + s_num[2] + s_num[3];
        const float bd = s_den[0] + s_den[1] + s_den[2] + s_den[3];
        atomicAdd(&acc[0], bn);
        atomicAdd(&acc[1], bd);
    }
}

__global__ void mae_finalize_kernel(const float* __restrict__ acc,
                                    float* __restrict__ out)
{
    out[0] = acc[0] / acc[1];
}

extern "C" void kernel_launch(void* const* d_in, const int* in_sizes, int n_in,
                              void* d_out, int out_size, void* d_ws, size_t ws_size,
                              hipStream_t stream)
{
    const float* y_pred = (const float*)d_in[0];
    const float* y_true = (const float*)d_in[1];
    float* out = (float*)d_out;
    float* acc = (float*)d_ws;
    const int n = in_sizes[0];

    // d_ws is re-poisoned to 0xAA before every timed launch — zero it each call
    hipMemsetAsync(acc, 0, 2 * sizeof(float), stream);

    const int block = 256;
    // 2048 blocks x 4 waves = 32 waves/CU across 256 CUs (max occupancy)
    int grid = 2048;
    const int n4 = n >> 2;
    if (grid > (n4 + block - 1) / block) grid = (n4 + block - 1) / block;
    if (grid < 1) grid = 1;

    mae_partial_kernel<<<grid, block, 0, stream>>>(y_pred, y_true, acc, n);
    mae_finalize_kernel<<<1, 1, 0, stream>>>(acc, out);
}